// Round 17
// baseline (36.633 us; speedup 1.0000x reference)
//
#include <hip/hip_runtime.h>
#include <hip/hip_bf16.h>
#include <stdint.h>

#define NDIM 4096
#define CDIM 64
#define NSPLIT 8
#define SPAN (NDIM / NSPLIT)   // 512 keys per split
#define NQ4 (SPAN / 32)        // 16 quarters per block
#define LOG2E 1.44269504088896f

typedef float f32x4 __attribute__((ext_vector_type(4)));
typedef float f32x16 __attribute__((ext_vector_type(16)));
typedef short bf16x8 __attribute__((ext_vector_type(8)));
union U4B { uint4 u; bf16x8 b; };

// single-instruction packed f32->bf16 (RNE), lo -> bits[15:0], hi -> bits[31:16]
static __device__ __forceinline__ uint32_t cvtpk(float lo, float hi) {
  uint32_t r;
  asm("v_cvt_pk_bf16_f32 %0, %1, %2" : "=v"(r) : "v"(lo), "v"(hi));
  return r;
}
static __device__ __forceinline__ uint16_t f2bf(float f) {
  uint32_t r;
  asm("v_cvt_pk_bf16_f32 %0, %1, %1" : "=v"(r) : "v"(f));
  return (uint16_t)r;
}
static __device__ __forceinline__ float fexp2(float x) {
  return __builtin_amdgcn_exp2f(x);   // raw v_exp_f32
}

// ---------------- Kernel 1: projections via MFMA (fp32 -> bf16) -------------
// 512 blocks x 256 threads (4 waves). Block = (b, 32 columns); wave roles:
// w0: V rows 0-31, w1: V rows 32-63, w2: Q (from x_opt), w3: K (from x_sar).
// V written key-blocked vf2[b][kb=key/16][ch][kk=key%16]; K packed [n][8].
__global__ __launch_bounds__(256) void proj_kernel(
    const float* __restrict__ x_opt, const float* __restrict__ x_sar,
    const float* __restrict__ wq, const float* __restrict__ bq,
    const float* __restrict__ wk, const float* __restrict__ bk,
    const float* __restrict__ wvp, const float* __restrict__ bv,
    uint16_t* __restrict__ qf, uint16_t* __restrict__ kfp,
    uint16_t* __restrict__ vf2)
{
  const int tid = threadIdx.x;
  const int w = tid >> 6;       // wave role
  const int l = tid & 63;
  const int x = l & 31;
  const int hi = l >> 5;

  const int id = blockIdx.x;
  const int b = id >> 7;
  const int n0 = (id & 127) * 32;
  const size_t xbase = (size_t)b * CDIM * NDIM;

  // ---- X B-fragment (lane = col n0+x, regs = 8 k along kc*16 + 8hi + j)
  const float* xsrc = (w == 2) ? x_opt : x_sar;
  bf16x8 xB[4];
#pragma unroll
  for (int kc = 0; kc < 4; kc++) {
    float sv[8];
#pragma unroll
    for (int j = 0; j < 8; j++)
      sv[j] = xsrc[xbase + (size_t)(kc * 16 + hi * 8 + j) * NDIM + n0 + x];
    U4B us;
    us.u = make_uint4(cvtpk(sv[0], sv[1]), cvtpk(sv[2], sv[3]),
                      cvtpk(sv[4], sv[5]), cvtpk(sv[6], sv[7]));
    xB[kc] = us.b;
  }

  // ---- W A-fragment
  bf16x8 aF[4];
#pragma unroll
  for (int kc = 0; kc < 4; kc++) {
    U4B ua;
    ua.u = make_uint4(0u, 0u, 0u, 0u);
    if (w < 2) {
      const float* wr = wvp + (w * 32 + x) * 64 + kc * 16 + hi * 8;
      float4 wa = ((const float4*)wr)[0];
      float4 wb = ((const float4*)wr)[1];
      ua.u = make_uint4(cvtpk(wa.x, wa.y), cvtpk(wa.z, wa.w),
                        cvtpk(wb.x, wb.y), cvtpk(wb.z, wb.w));
    } else if (x < 8) {
      const float* wr = ((w == 2) ? wq : wk) + x * 64 + kc * 16 + hi * 8;
      float4 wa = ((const float4*)wr)[0];
      float4 wb = ((const float4*)wr)[1];
      ua.u = make_uint4(cvtpk(wa.x, wa.y), cvtpk(wa.z, wa.w),
                        cvtpk(wb.x, wb.y), cvtpk(wb.z, wb.w));
    }
    aF[kc] = ua.b;
  }

  const f32x16 z16 = {0.f,0.f,0.f,0.f, 0.f,0.f,0.f,0.f,
                      0.f,0.f,0.f,0.f, 0.f,0.f,0.f,0.f};
  f32x16 acc = z16;
#pragma unroll
  for (int kc = 0; kc < 4; kc++)
    acc = __builtin_amdgcn_mfma_f32_32x32x16_bf16(aF[kc], xB[kc], acc, 0, 0, 0);

  if (w < 2) {
    // V stores into blocked layout: kb = (n0+x)/16, kk = (n0+x)%16
    const size_t kbbase = (size_t)b * 256 + (n0 >> 4) + (x >> 4);
    const int kk = x & 15;
#pragma unroll
    for (int r = 0; r < 16; r++) {
      const int row = w * 32 + (r & 3) + 8 * (r >> 2) + 4 * hi;
      vf2[(kbbase * 64 + row) * 16 + kk] = f2bf(acc[r] + bv[row]);
    }
  } else if (w == 2) {
    // Q store: regs 0-3 hold d = 4hi + r; layout [n][16], zero upper 8
    float gv[4];
#pragma unroll
    for (int r = 0; r < 4; r++) gv[r] = (acc[r] + bq[4 * hi + r]) * LOG2E;
    const size_t nrow = ((size_t)b * NDIM + n0 + x) * 16;
    uint2 st;
    st.x = cvtpk(gv[0], gv[1]); st.y = cvtpk(gv[2], gv[3]);
    *(uint2*)(qf + nrow + hi * 4) = st;
    if (hi == 0) {
      const uint4 z4 = make_uint4(0u, 0u, 0u, 0u);
      *(uint4*)(qf + nrow + 8) = z4;
    }
  } else {
    // K store: packed [n][8] (real d only)
    float gv[4];
#pragma unroll
    for (int r = 0; r < 4; r++) gv[r] = acc[r] + bk[4 * hi + r];
    uint2 st;
    st.x = cvtpk(gv[0], gv[1]); st.y = cvtpk(gv[2], gv[3]);
    *(uint2*)(kfp + ((size_t)b * NDIM + n0 + x) * 8 + hi * 4) = st;
  }
}

// ------------- Kernel 2: flash attention partial (K-split) -----------
// 1024 blocks x 256 threads, sp = id&7 pins KV span to one XCD's L2.
// NO LDS, NO barriers; coalesced blocked-V + packed-K; 1-quarter register
// lookahead. QUARTER-SKEW: block starts its walk at quarter (qb & 15) and
// wraps (legal: no-max softmax is order-independent) so the 128 blocks of
// an XCD read DIFFERENT 4.5KB windows simultaneously -> no L2 hot-banking.
__global__ __launch_bounds__(256, 4) void attn_kernel(
    const uint16_t* __restrict__ qf, const uint16_t* __restrict__ kfp,
    const uint16_t* __restrict__ vf2,
    uint16_t* __restrict__ po2, float* __restrict__ ls)
{
  const int tid = threadIdx.x;
  const int w = tid >> 6;
  const int l = tid & 63;
  const int x = l & 31;       // query col (S,O) / key row (K-frag) / channel (V-frag)
  const int hi = l >> 5;

  const int id = blockIdx.x;           // 1024 = 8 sp x 32 qb x 4 b
  const int sp = id & 7;
  const int qb = (id >> 3) & 31;
  const int b = id >> 8;

  const int n0 = qb * 128;
  const int qrow = n0 + w * 32 + x;
  const int skew = qb & 15;

  U4B qfr;
  qfr.u = *(const uint4*)(qf + ((size_t)b * NDIM + qrow) * 16 + hi * 8);

  // uniform bases + per-lane offsets (saddr + voffset form)
  const uint16_t* ksb = kfp + ((size_t)b * NDIM + sp * SPAN) * 8;
  const uint16_t* vsb = vf2 + (((size_t)b * 256 + sp * 32) * 64) * 16;
  const int klane = x * 8;              // K[key=x][0..7]
  const int vlane = x * 16 + hi * 8;    // V ch=x, kk=8hi..

  const f32x16 z16 = {0.f,0.f,0.f,0.f, 0.f,0.f,0.f,0.f,
                      0.f,0.f,0.f,0.f, 0.f,0.f,0.f,0.f};
  f32x16 oacc0 = z16, oacc1 = z16;
  float lacc[4] = {0.f, 0.f, 0.f, 0.f};

  // prologue: quarter-0/1 (skewed) K and V fragments
  uint4 kA, vA0, vA1, vA2, vA3;
  {
    const int e0 = skew;
    kA  = *(const uint4*)(ksb + e0 * 256 + klane);
    vA0 = *(const uint4*)(vsb + e0 * 2048 + vlane);
    vA1 = *(const uint4*)(vsb + e0 * 2048 + 512 + vlane);
    vA2 = *(const uint4*)(vsb + e0 * 2048 + 1024 + vlane);
    vA3 = *(const uint4*)(vsb + e0 * 2048 + 1536 + vlane);
  }

#pragma unroll
  for (int gq = 0; gq < NQ4; gq++) {
    // ---- prefetch quarter gq+1 (wraps mod 16; the wraps at gq=15 produce
    // a dead value -- address always valid)
    const int e1 = (gq + 1 + skew) & 15;
    uint4 kn   = *(const uint4*)(ksb + e1 * 256 + klane);
    uint4 vn0  = *(const uint4*)(vsb + e1 * 2048 + vlane);
    uint4 vn1  = *(const uint4*)(vsb + e1 * 2048 + 512 + vlane);
    uint4 vn2  = *(const uint4*)(vsb + e1 * 2048 + 1024 + vlane);
    uint4 vn3  = *(const uint4*)(vsb + e1 * 2048 + 1536 + vlane);

    // ---- scores S^T (32 keys x 32 queries), lane(q=x,hi):
    // key = (r&3) + 8*(r>>2) + 4hi. K hi-half garbage x Q zero = 0.
    U4B ka; ka.u = kA;
    f32x16 s = __builtin_amdgcn_mfma_f32_32x32x16_bf16(ka.b, qfr.b, z16, 0, 0, 0);

    // ---- fused p = exp2(s) -> bf16 pack -> row-sum (2 live p floats)
    uint32_t W[8];
#pragma unroll
    for (int j = 0; j < 8; j++) {
      const float p0 = fexp2(s[2 * j]);
      const float p1 = fexp2(s[2 * j + 1]);
      W[j] = cvtpk(p0, p1);
      lacc[j & 3] += p0 + p1;
    }

    // ---- PV: O^T += V^T . P^T (2 sub-chunks x 2 channel-blocks)
    __builtin_amdgcn_s_setprio(1);
    {
      uint32_t a0 = W[0], b0 = W[2], a1 = W[1], b1 = W[3];
      asm("v_permlane32_swap_b32 %0, %1" : "+v"(a0), "+v"(b0));
      asm("v_permlane32_swap_b32 %0, %1" : "+v"(a1), "+v"(b1));
      U4B pf, va, vb;
      pf.u = make_uint4(a0, a1, b0, b1);
      va.u = vA0; vb.u = vA1;
      oacc0 = __builtin_amdgcn_mfma_f32_32x32x16_bf16(va.b, pf.b, oacc0, 0, 0, 0);
      oacc1 = __builtin_amdgcn_mfma_f32_32x32x16_bf16(vb.b, pf.b, oacc1, 0, 0, 0);
    }
    {
      uint32_t a0 = W[4], b0 = W[6], a1 = W[5], b1 = W[7];
      asm("v_permlane32_swap_b32 %0, %1" : "+v"(a0), "+v"(b0));
      asm("v_permlane32_swap_b32 %0, %1" : "+v"(a1), "+v"(b1));
      U4B pf, va, vb;
      pf.u = make_uint4(a0, a1, b0, b1);
      va.u = vA2; vb.u = vA3;
      oacc0 = __builtin_amdgcn_mfma_f32_32x32x16_bf16(va.b, pf.b, oacc0, 0, 0, 0);
      oacc1 = __builtin_amdgcn_mfma_f32_32x32x16_bf16(vb.b, pf.b, oacc1, 0, 0, 0);
    }
    __builtin_amdgcn_s_setprio(0);

    kA = kn; vA0 = vn0; vA1 = vn1; vA2 = vn2; vA3 = vn3;
  }

  // ---- epilogue: raw partial O^T, channel-major po2[(sp*256+b*64+c)][n]
  {
    uint16_t* pb = po2 + ((size_t)(sp * 256 + b * 64 + hi * 4)) * NDIM + qrow;
#pragma unroll
    for (int r = 0; r < 16; r++) {
      const size_t off = (size_t)((r & 3) + 8 * (r >> 2)) * NDIM;
      pb[off] = f2bf(oacc0[r]);
      pb[off + (size_t)32 * NDIM] = f2bf(oacc1[r]);
    }
  }
  float ltot = (lacc[0] + lacc[1]) + (lacc[2] + lacc[3]);
  ltot += __shfl_xor(ltot, 32);
  if (hi == 0)
    ls[((size_t)sp * 4 + b) * NDIM + qrow] = ltot;
}

// ---------------- Kernel 3: split merge + gamma*O + residual ----------------
// 512 blocks x 256 threads; one thread = 8 consecutive n for one (b,c).
// All reads/writes fully coalesced along n; no LDS.
__global__ __launch_bounds__(256) void merge_kernel(
    const uint16_t* __restrict__ po2, const float* __restrict__ ls,
    const float* __restrict__ x_opt, const float* __restrict__ gamma,
    float* __restrict__ out)
{
  const int idx = blockIdx.x * 256 + threadIdx.x;   // 131072 threads
  const int n8 = (idx & 511) << 3;
  const int row = idx >> 9;              // b*64 + c
  const int b = row >> 6;

  float acc[8] = {0.f, 0.f, 0.f, 0.f, 0.f, 0.f, 0.f, 0.f};
  f32x4 ws0 = {0.f, 0.f, 0.f, 0.f};
  f32x4 ws1 = {0.f, 0.f, 0.f, 0.f};
#pragma unroll
  for (int s = 0; s < NSPLIT; s++) {
    const uint4 pv = *(const uint4*)(po2 + ((size_t)s * 256 + row) * NDIM + n8);
    const uint32_t* pw = (const uint32_t*)&pv;
#pragma unroll
    for (int j = 0; j < 4; j++) {
      acc[j * 2 + 0] += __uint_as_float(pw[j] << 16);
      acc[j * 2 + 1] += __uint_as_float(pw[j] & 0xFFFF0000u);
    }
    const float* lp = ls + ((size_t)s * 4 + b) * NDIM + n8;
    ws0 += *(const f32x4*)(lp);
    ws1 += *(const f32x4*)(lp + 4);
  }
  const float gm = gamma[0];
  const float* xp = x_opt + (size_t)row * NDIM + n8;
  float* op = out + (size_t)row * NDIM + n8;
  float4 x0 = ((const float4*)xp)[0];
  float4 x1 = ((const float4*)xp)[1];
  float4 o0, o1;
  o0.x = gm * acc[0] / ws0[0] + x0.x;
  o0.y = gm * acc[1] / ws0[1] + x0.y;
  o0.z = gm * acc[2] / ws0[2] + x0.z;
  o0.w = gm * acc[3] / ws0[3] + x0.w;
  o1.x = gm * acc[4] / ws1[0] + x1.x;
  o1.y = gm * acc[5] / ws1[1] + x1.y;
  o1.z = gm * acc[6] / ws1[2] + x1.z;
  o1.w = gm * acc[7] / ws1[3] + x1.w;
  ((float4*)op)[0] = o0;
  ((float4*)op)[1] = o1;
}

extern "C" void kernel_launch(void* const* d_in, const int* in_sizes, int n_in,
                              void* d_out, int out_size, void* d_ws, size_t ws_size,
                              hipStream_t stream) {
  const float* x_opt = (const float*)d_in[0];
  const float* x_sar = (const float*)d_in[1];
  const float* wq    = (const float*)d_in[2];
  const float* bq    = (const float*)d_in[3];
  const float* wk    = (const float*)d_in[4];
  const float* bk    = (const float*)d_in[5];
  const float* wvp   = (const float*)d_in[6];
  const float* bv    = (const float*)d_in[7];
  const float* gamma = (const float*)d_in[8];
  float* outp = (float*)d_out;

  // ws: qf 512K | kfp 256K(+256K pad) | vf2 2M | po2(bf16) 16M | ls 512K
  uint16_t* qf  = (uint16_t*)d_ws;
  uint16_t* kfp = (uint16_t*)((char*)d_ws + 524288);
  uint16_t* vf2 = (uint16_t*)((char*)d_ws + 1048576);
  uint16_t* po2 = (uint16_t*)((char*)d_ws + 3145728);
  float* lsp    = (float*)((char*)d_ws + 19922944);

  proj_kernel<<<512, 256, 0, stream>>>(x_opt, x_sar, wq, bq, wk, bk, wvp, bv,
                                       qf, kfp, vf2);
  attn_kernel<<<1024, 256, 0, stream>>>(qf, kfp, vf2, po2, lsp);
  merge_kernel<<<512, 256, 0, stream>>>(po2, lsp, x_opt, gamma, outp);
}